// Round 3
// baseline (1212.351 us; speedup 1.0000x reference)
//
#include <hip/hip_runtime.h>
#include <hip/hip_bf16.h>

#define B_ 8
#define D_ 40
#define T_ 192
#define G_ 256
#define U_ 768   // 3*UNITS
#define H_ 256   // UNITS

typedef _Float16 half2_t __attribute__((ext_vector_type(2)));
typedef _Float16 half8_t __attribute__((ext_vector_type(8)));

__device__ inline float fdot2f(half2_t a, half2_t b, float c){
#if __has_builtin(__builtin_amdgcn_fdot2)
  return __builtin_amdgcn_fdot2(a, b, c, false);
#else
  return c + (float)a.x*(float)b.x + (float)a.y*(float)b.y;
#endif
}

__device__ inline float sigmoidf_(float x){
  return 1.0f/(1.0f+__expf(-x));
}
__device__ inline float tanhf_(float x){
  float ax = fabsf(x);
  float e = __expf(-2.0f*ax);
  float t = (1.0f-e)/(1.0f+e);
  return copysignf(t, x);
}

// ---------------- Kernel 1: single-channel interp + per-(b,d) mean ----------
__global__ __launch_bounds__(256) void k_interp(
    const float* __restrict__ times, const float* __restrict__ values,
    const float* __restrict__ meas, const float* __restrict__ grid,
    const float* __restrict__ ksic,
    float* __restrict__ y, float* __restrict__ w, float* __restrict__ ytr,
    float* __restrict__ mean){
  int bd = blockIdx.x;            // b*D_+d
  int b = bd / D_, d = bd % D_;
  int g = threadIdx.x;
  __shared__ float tt[T_], vv[T_], mm[T_];
  __shared__ float red[256];
  if (g < T_){
    tt[g] = times[bd*T_+g];
    vv[g] = values[bd*T_+g];
    mm[g] = meas[bd*T_+g];
  }
  __syncthreads();
  float alpha = log1pf(__expf(ksic[d]));   // softplus
  float tg = grid[b*G_+g];
  float nmin = 3.4e38f;
  for (int t=0;t<T_;t++){
    if (mm[t] > 0.0f){
      float dd = tt[t]-tg;
      nmin = fminf(nmin, dd*dd);
    }
  }
  float s1=0.f, sv1=0.f, s10=0.f, sv10=0.f;
  for (int t=0;t<T_;t++){
    if (mm[t] > 0.0f){
      float dd = tt[t]-tg;
      float n = dd*dd - nmin;               // >= 0
      float e1  = __expf(-alpha*n);
      float e10 = __expf(-10.0f*alpha*n);
      s1 += e1;  sv1 += e1*vv[t];
      s10 += e10; sv10 += e10*vv[t];
    }
  }
  float yv = sv1/s1;
  float wv = -alpha*nmin + __logf(s1);
  y[bd*G_+g]   = yv;
  w[bd*G_+g]   = wv;
  ytr[bd*G_+g] = sv10/s10;
  red[g] = yv;
  __syncthreads();
  for (int s=128;s>0;s>>=1){
    if (g<s) red[g]+=red[g+s];
    __syncthreads();
  }
  if (g==0) mean[bd] = red[0]*(1.0f/(float)G_);
}

// ---------------- Kernel 2: cross-channel interp + feats + x_proj -----------
__global__ __launch_bounds__(256) void k_cross(
    const float* __restrict__ y, const float* __restrict__ w,
    const float* __restrict__ ytr, const float* __restrict__ mean,
    const float* __restrict__ crossW, const float* __restrict__ Wx,
    const float* __restrict__ gru_b, const int* __restrict__ lens,
    float* __restrict__ xproj){
  int bg = blockIdx.x;              // b*G_+g
  int b = bg >> 8, g = bg & 255;
  if (g >= lens[b]) return;         // x_proj unused beyond length
  __shared__ float wd[D_], yd[D_], ytrd[D_], md[D_], cc[D_], feats[3*D_];
  __shared__ float wstat[2];
  int tid = threadIdx.x;
  if (tid < D_){
    int idx = (b*D_+tid)*G_+g;
    wd[tid]=w[idx]; yd[tid]=y[idx]; ytrd[tid]=ytr[idx]; md[tid]=mean[b*D_+tid];
  }
  __syncthreads();
  if (tid==0){
    float mx=-3.4e38f;
    for (int d2=0;d2<D_;d2++) mx = fmaxf(mx, wd[d2]);
    float s=0.f;
    for (int d2=0;d2<D_;d2++) s += __expf(wd[d2]-mx);
    wstat[0]=mx; wstat[1]=1.0f/s;
  }
  __syncthreads();
  if (tid<D_){
    float sw = __expf(wd[tid]-wstat[0])*wstat[1];
    cc[tid] = sw*(yd[tid]-md[tid]);
  }
  __syncthreads();
  if (tid<D_){
    float acc=0.f;
    for (int d2=0;d2<D_;d2++) acc += cc[d2]*crossW[d2*D_+tid];
    float rep = acc + md[tid];
    feats[tid]       = rep;                   // rep1
    feats[D_+tid]    = __expf(wd[tid]);       // intensity
    feats[2*D_+tid]  = ytrd[tid]-rep;         // y_trans - rep1
  }
  __syncthreads();
  for (int jj=0;jj<3;jj++){
    int j = tid + jj*256;
    float acc = gru_b[j];
    #pragma unroll 4
    for (int i=0;i<3*D_;i++) acc += feats[i]*Wx[i*U_+j];
    xproj[(size_t)bg*U_ + j] = acc;
  }
}

// ---------------- Kernel 3: demo MLP -> h0 ----------------------------------
__global__ __launch_bounds__(256) void k_demo(
    const float* __restrict__ demo, const float* __restrict__ W1,
    const float* __restrict__ b1, const float* __restrict__ W2,
    const float* __restrict__ b2, float* __restrict__ h0){
  __shared__ float dl[B_*16];
  __shared__ float hid[B_*H_];
  int u = threadIdx.x;
  if (u < B_*16) dl[u] = demo[u];
  __syncthreads();
  float acc[B_];
  #pragma unroll
  for (int b=0;b<B_;b++) acc[b]=b1[u];
  for (int i=0;i<16;i++){
    float w1 = W1[i*H_+u];
    #pragma unroll
    for (int b=0;b<B_;b++) acc[b] += dl[b*16+i]*w1;
  }
  #pragma unroll
  for (int b=0;b<B_;b++) hid[b*H_+u] = fmaxf(acc[b],0.f);
  __syncthreads();
  #pragma unroll
  for (int b=0;b<B_;b++) acc[b]=b2[u];
  for (int k=0;k<H_;k++){
    float w2 = W2[k*H_+u];
    #pragma unroll
    for (int b=0;b<B_;b++) acc[b] += hid[b*H_+k]*w2;
  }
  #pragma unroll
  for (int b=0;b<B_;b++) h0[b*H_+u]=acc[b];
}

// ---------------- Kernel 4: masked GRU (one block per batch) ----------------
// 256 threads (4 waves, 1 wave/SIMD -> 512-VGPR cap). Thread j owns hidden
// unit j: Wh columns j (z), j+256 (r), j+512 (h) live in registers as f16x2
// (3*128 = 384 VGPRs + ~40 working, fits without spilling). Gates computed
// fully in-register; h double-buffered in LDS as f16 -> ONE barrier per step.
__global__ __launch_bounds__(256,1) void k_gru(
    const float* __restrict__ Wh, const float* __restrict__ gru_b,
    const float* __restrict__ xproj, const float* __restrict__ h0,
    const int* __restrict__ lens, const float* __restrict__ outW,
    const float* __restrict__ outb, float* __restrict__ out){
  int b = blockIdx.x;
  int j = threadIdx.x;
  __shared__ half8_t hbuf[2][H_/8];   // double-buffered h (f16 octets)
  __shared__ float red[H_];

  // preload Wh columns j, j+H, j+2H into registers (f16 packed, static idx)
  half2_t wz[H_/2], wr[H_/2], wh[H_/2];
  #pragma unroll
  for (int k=0;k<H_/2;k++){
    float a0 = Wh[(2*k)*U_ + j];
    float a1 = Wh[(2*k+1)*U_ + j];
    half2_t p; p.x=(_Float16)a0; p.y=(_Float16)a1; wz[k]=p;
  }
  #pragma unroll
  for (int k=0;k<H_/2;k++){
    float a0 = Wh[(2*k)*U_ + H_ + j];
    float a1 = Wh[(2*k+1)*U_ + H_ + j];
    half2_t p; p.x=(_Float16)a0; p.y=(_Float16)a1; wr[k]=p;
  }
  #pragma unroll
  for (int k=0;k<H_/2;k++){
    float a0 = Wh[(2*k)*U_ + 2*H_ + j];
    float a1 = Wh[(2*k+1)*U_ + 2*H_ + j];
    half2_t p; p.x=(_Float16)a0; p.y=(_Float16)a1; wh[k]=p;
  }
  float brz = gru_b[U_ + j];
  float brr = gru_b[U_ + H_ + j];
  float brh = gru_b[U_ + 2*H_ + j];

  float hj = h0[b*H_ + j];
  ((_Float16*)hbuf[0])[j] = (_Float16)hj;
  int len = lens[b];
  const float* xbase = xproj + (size_t)b*G_*U_;
  __syncthreads();

  float xpz = xbase[j];
  float xpr = xbase[H_ + j];
  float xph = xbase[2*H_ + j];

  for (int g=0; g<len; g++){
    const half8_t* hcur = hbuf[g & 1];
    // prefetch next step's x-proj elements (latency hides under dot loop)
    float nxz=0.f, nxr=0.f, nxh=0.f;
    if (g+1 < len){
      const float* xn = xbase + (size_t)(g+1)*U_;
      nxz = xn[j]; nxr = xn[H_ + j]; nxh = xn[2*H_ + j];
    }
    float az0=brz, az1=0.f, az2=0.f, az3=0.f;
    float ar0=brr, ar1=0.f, ar2=0.f, ar3=0.f;
    float ah0=brh, ah1=0.f, ah2=0.f, ah3=0.f;
    #pragma unroll
    for (int kk=0;kk<H_/8;kk++){
      half8_t hv = hcur[kk];                 // ds_read_b128, broadcast
      half2_t p0 = {hv[0],hv[1]};
      half2_t p1 = {hv[2],hv[3]};
      half2_t p2 = {hv[4],hv[5]};
      half2_t p3 = {hv[6],hv[7]};
      az0 = fdot2f(p0, wz[4*kk+0], az0);
      ar0 = fdot2f(p0, wr[4*kk+0], ar0);
      ah0 = fdot2f(p0, wh[4*kk+0], ah0);
      az1 = fdot2f(p1, wz[4*kk+1], az1);
      ar1 = fdot2f(p1, wr[4*kk+1], ar1);
      ah1 = fdot2f(p1, wh[4*kk+1], ah1);
      az2 = fdot2f(p2, wz[4*kk+2], az2);
      ar2 = fdot2f(p2, wr[4*kk+2], ar2);
      ah2 = fdot2f(p2, wh[4*kk+2], ah2);
      az3 = fdot2f(p3, wz[4*kk+3], az3);
      ar3 = fdot2f(p3, wr[4*kk+3], ar3);
      ah3 = fdot2f(p3, wh[4*kk+3], ah3);
    }
    float az = (az0+az1)+(az2+az3);
    float ar = (ar0+ar1)+(ar2+ar3);
    float ah = (ah0+ah1)+(ah2+ah3);
    float z    = sigmoidf_(xpz + az);
    float r    = sigmoidf_(xpr + ar);
    float cand = tanhf_(xph + r*ah);
    hj = z*hj + (1.0f-z)*cand;
    ((_Float16*)hbuf[(g+1)&1])[j] = (_Float16)hj;
    __syncthreads();          // writes visible before next step's reads;
                              // also fences next step's overwrite of hbuf[g&1]
    xpz = nxz; xpr = nxr; xph = nxh;
  }

  // out = sigmoid(h . outW + outb)
  red[j] = hj*outW[j];
  __syncthreads();
  for (int st=128;st>0;st>>=1){
    if (j<st) red[j]+=red[j+st];
    __syncthreads();
  }
  if (j==0) out[b] = sigmoidf_(red[0]+outb[0]);
}

extern "C" void kernel_launch(void* const* d_in, const int* in_sizes, int n_in,
                              void* d_out, int out_size, void* d_ws, size_t ws_size,
                              hipStream_t stream) {
  const float* demo   = (const float*)d_in[0];
  const float* times  = (const float*)d_in[1];
  const float* values = (const float*)d_in[2];
  const float* meas   = (const float*)d_in[3];
  const float* grid   = (const float*)d_in[4];
  const float* ksic   = (const float*)d_in[5];
  const float* crossW = (const float*)d_in[6];
  const float* dW1    = (const float*)d_in[7];
  const float* db1    = (const float*)d_in[8];
  const float* dW2    = (const float*)d_in[9];
  const float* db2    = (const float*)d_in[10];
  const float* gWx    = (const float*)d_in[11];
  const float* gWh    = (const float*)d_in[12];
  const float* gb     = (const float*)d_in[13];
  const float* outW   = (const float*)d_in[14];
  const float* outb   = (const float*)d_in[15];
  const int*   lens   = (const int*)d_in[16];
  float* out = (float*)d_out;

  float* ws   = (float*)d_ws;
  float* y    = ws;                        // B*D*G
  float* w    = y    + B_*D_*G_;
  float* ytr  = w    + B_*D_*G_;
  float* mean = ytr  + B_*D_*G_;
  float* h0   = mean + B_*D_;
  float* xprj = h0   + B_*H_;              // B*G*768

  k_interp<<<B_*D_, 256, 0, stream>>>(times, values, meas, grid, ksic, y, w, ytr, mean);
  k_demo  <<<1,     256, 0, stream>>>(demo, dW1, db1, dW2, db2, h0);
  k_cross <<<B_*G_, 256, 0, stream>>>(y, w, ytr, mean, crossW, gWx, gb, lens, xprj);
  k_gru   <<<B_,    256, 0, stream>>>(gWh, gb, xprj, h0, lens, outW, outb, out);
}

// Round 4
// 481.851 us; speedup vs baseline: 2.5160x; 2.5160x over previous
//
#include <hip/hip_runtime.h>
#include <hip/hip_bf16.h>

#define B_ 8
#define D_ 40
#define T_ 192
#define G_ 256
#define U_ 768   // 3*UNITS
#define H_ 256   // UNITS

typedef _Float16 half2_t __attribute__((ext_vector_type(2)));
typedef _Float16 half8_t __attribute__((ext_vector_type(8)));

__device__ inline float fdot2f(half2_t a, half2_t b, float c){
#if __has_builtin(__builtin_amdgcn_fdot2)
  return __builtin_amdgcn_fdot2(a, b, c, false);
#else
  return c + (float)a.x*(float)b.x + (float)a.y*(float)b.y;
#endif
}

__device__ inline float sigmoidf_(float x){
  return 1.0f/(1.0f+__expf(-x));
}
__device__ inline float tanhf_(float x){
  float ax = fabsf(x);
  float e = __expf(-2.0f*ax);
  float t = (1.0f-e)/(1.0f+e);
  return copysignf(t, x);
}

// ---------------- Kernel 1: single-channel interp + per-(b,d) mean ----------
__global__ __launch_bounds__(256) void k_interp(
    const float* __restrict__ times, const float* __restrict__ values,
    const float* __restrict__ meas, const float* __restrict__ grid,
    const float* __restrict__ ksic,
    float* __restrict__ y, float* __restrict__ w, float* __restrict__ ytr,
    float* __restrict__ mean){
  int bd = blockIdx.x;            // b*D_+d
  int b = bd / D_, d = bd % D_;
  int g = threadIdx.x;
  __shared__ float tt[T_], vv[T_], mm[T_];
  __shared__ float red[256];
  if (g < T_){
    tt[g] = times[bd*T_+g];
    vv[g] = values[bd*T_+g];
    mm[g] = meas[bd*T_+g];
  }
  __syncthreads();
  float alpha = log1pf(__expf(ksic[d]));   // softplus
  float tg = grid[b*G_+g];
  float nmin = 3.4e38f;
  for (int t=0;t<T_;t++){
    if (mm[t] > 0.0f){
      float dd = tt[t]-tg;
      nmin = fminf(nmin, dd*dd);
    }
  }
  float s1=0.f, sv1=0.f, s10=0.f, sv10=0.f;
  for (int t=0;t<T_;t++){
    if (mm[t] > 0.0f){
      float dd = tt[t]-tg;
      float n = dd*dd - nmin;               // >= 0
      float e1  = __expf(-alpha*n);
      float e10 = __expf(-10.0f*alpha*n);
      s1 += e1;  sv1 += e1*vv[t];
      s10 += e10; sv10 += e10*vv[t];
    }
  }
  float yv = sv1/s1;
  float wv = -alpha*nmin + __logf(s1);
  y[bd*G_+g]   = yv;
  w[bd*G_+g]   = wv;
  ytr[bd*G_+g] = sv10/s10;
  red[g] = yv;
  __syncthreads();
  for (int s=128;s>0;s>>=1){
    if (g<s) red[g]+=red[g+s];
    __syncthreads();
  }
  if (g==0) mean[bd] = red[0]*(1.0f/(float)G_);
}

// ---------------- Kernel 2: cross-channel interp + feats + x_proj -----------
__global__ __launch_bounds__(256) void k_cross(
    const float* __restrict__ y, const float* __restrict__ w,
    const float* __restrict__ ytr, const float* __restrict__ mean,
    const float* __restrict__ crossW, const float* __restrict__ Wx,
    const float* __restrict__ gru_b, const int* __restrict__ lens,
    float* __restrict__ xproj){
  int bg = blockIdx.x;              // b*G_+g
  int b = bg >> 8, g = bg & 255;
  if (g >= lens[b]) return;         // x_proj unused beyond length
  __shared__ float wd[D_], yd[D_], ytrd[D_], md[D_], cc[D_], feats[3*D_];
  __shared__ float wstat[2];
  int tid = threadIdx.x;
  if (tid < D_){
    int idx = (b*D_+tid)*G_+g;
    wd[tid]=w[idx]; yd[tid]=y[idx]; ytrd[tid]=ytr[idx]; md[tid]=mean[b*D_+tid];
  }
  __syncthreads();
  if (tid==0){
    float mx=-3.4e38f;
    for (int d2=0;d2<D_;d2++) mx = fmaxf(mx, wd[d2]);
    float s=0.f;
    for (int d2=0;d2<D_;d2++) s += __expf(wd[d2]-mx);
    wstat[0]=mx; wstat[1]=1.0f/s;
  }
  __syncthreads();
  if (tid<D_){
    float sw = __expf(wd[tid]-wstat[0])*wstat[1];
    cc[tid] = sw*(yd[tid]-md[tid]);
  }
  __syncthreads();
  if (tid<D_){
    float acc=0.f;
    for (int d2=0;d2<D_;d2++) acc += cc[d2]*crossW[d2*D_+tid];
    float rep = acc + md[tid];
    feats[tid]       = rep;                   // rep1
    feats[D_+tid]    = __expf(wd[tid]);       // intensity
    feats[2*D_+tid]  = ytrd[tid]-rep;         // y_trans - rep1
  }
  __syncthreads();
  for (int jj=0;jj<3;jj++){
    int j = tid + jj*256;
    float acc = gru_b[j];
    #pragma unroll 4
    for (int i=0;i<3*D_;i++) acc += feats[i]*Wx[i*U_+j];
    xproj[(size_t)bg*U_ + j] = acc;
  }
}

// ---------------- Kernel 3: demo MLP -> h0 ----------------------------------
__global__ __launch_bounds__(256) void k_demo(
    const float* __restrict__ demo, const float* __restrict__ W1,
    const float* __restrict__ b1, const float* __restrict__ W2,
    const float* __restrict__ b2, float* __restrict__ h0){
  __shared__ float dl[B_*16];
  __shared__ float hid[B_*H_];
  int u = threadIdx.x;
  if (u < B_*16) dl[u] = demo[u];
  __syncthreads();
  float acc[B_];
  #pragma unroll
  for (int b=0;b<B_;b++) acc[b]=b1[u];
  for (int i=0;i<16;i++){
    float w1 = W1[i*H_+u];
    #pragma unroll
    for (int b=0;b<B_;b++) acc[b] += dl[b*16+i]*w1;
  }
  #pragma unroll
  for (int b=0;b<B_;b++) hid[b*H_+u] = fmaxf(acc[b],0.f);
  __syncthreads();
  #pragma unroll
  for (int b=0;b<B_;b++) acc[b]=b2[u];
  for (int k=0;k<H_;k++){
    float w2 = W2[k*H_+u];
    #pragma unroll
    for (int b=0;b<B_;b++) acc[b] += hid[b*H_+k]*w2;
  }
  #pragma unroll
  for (int b=0;b<B_;b++) h0[b*H_+u]=acc[b];
}

// ---------------- Kernel 4: masked GRU (one block per batch) ----------------
// 512 threads, 8 waves, waves_per_eu pinned to 2 (full 256-VGPR budget).
// Per-thread weight storage: 192 VGPRs (arch max 256 addressable):
//   threads   0..255 (grpA): z-column j        (128 regs) + h-col j rows   0..127 (64 regs)
//   threads 256..511 (grpB): r-column j        (128 regs) + h-col j rows 128..255 (64 regs)
// h double-buffered f16 in LDS (broadcast ds_read_b128); partials via LDS;
// grpA does the gate update. 2 barriers/step.
__global__ __launch_bounds__(512) __attribute__((amdgpu_waves_per_eu(2,2)))
void k_gru(
    const float* __restrict__ Wh, const float* __restrict__ gru_b,
    const float* __restrict__ xproj, const float* __restrict__ h0,
    const int* __restrict__ lens, const float* __restrict__ outW,
    const float* __restrict__ outb, float* __restrict__ out){
  int b = blockIdx.x;
  int t = threadIdx.x;
  bool grpA = (t < H_);
  int j = grpA ? t : t - H_;
  int czr = grpA ? j : (H_ + j);       // z-col or r-col index
  int ch  = 2*H_ + j;                  // h-col index
  int k0  = grpA ? 0 : 128;            // h-half row offset

  __shared__ half8_t hbuf[2][H_/8];    // double-buffered h (f16 octets)
  __shared__ float sr[H_];             // r-gate dot partial (from grpB)
  __shared__ float sh1[H_];            // h-col second-half partial (from grpB)
  __shared__ float red[512];

  // ---- preload weights into registers (static indices, fully unrolled) ----
  half2_t wzr[128];
  #pragma unroll
  for (int k=0;k<128;k++){
    float a0 = Wh[(2*k)*U_ + czr];
    float a1 = Wh[(2*k+1)*U_ + czr];
    half2_t p; p.x=(_Float16)a0; p.y=(_Float16)a1; wzr[k]=p;
  }
  half2_t whh[64];
  #pragma unroll
  for (int k=0;k<64;k++){
    float a0 = Wh[(k0+2*k)*U_ + ch];
    float a1 = Wh[(k0+2*k+1)*U_ + ch];
    half2_t p; p.x=(_Float16)a0; p.y=(_Float16)a1; whh[k]=p;
  }
  float bzr = gru_b[U_ + czr];                  // brz (grpA) / brr (grpB)
  float bh  = grpA ? gru_b[U_ + ch] : 0.0f;     // brh counted once

  float hj = 0.0f;
  if (grpA){
    hj = h0[b*H_ + j];
    ((_Float16*)hbuf[0])[j] = (_Float16)hj;
  }
  int len = lens[b];
  const float* xbase = xproj + (size_t)b*G_*U_;
  __syncthreads();

  float xpz=0.f, xpr=0.f, xph=0.f;
  if (grpA){
    xpz = xbase[j]; xpr = xbase[H_+j]; xph = xbase[2*H_+j];
  }

  for (int g=0; g<len; g++){
    const half8_t* hcur = hbuf[g & 1];
    // prefetch next step's x (latency hides under dot loops)
    float nxz=0.f, nxr=0.f, nxh=0.f;
    if (grpA && (g+1 < len)){
      const float* xn = xbase + (size_t)(g+1)*U_;
      nxz = xn[j]; nxr = xn[H_+j]; nxh = xn[2*H_+j];
    }
    float a0=bzr, a1=0.f, a2=0.f, a3=0.f;   // z/r column accum
    float c0=bh,  c1=0.f, c2=0.f, c3=0.f;   // h half-column accum
    #pragma unroll
    for (int kk=0;kk<32;kk++){
      half8_t hv = hcur[kk];                 // ds_read_b128 broadcast
      half2_t p0 = {hv[0],hv[1]};
      half2_t p1 = {hv[2],hv[3]};
      half2_t p2 = {hv[4],hv[5]};
      half2_t p3 = {hv[6],hv[7]};
      a0 = fdot2f(p0, wzr[4*kk+0], a0);
      a1 = fdot2f(p1, wzr[4*kk+1], a1);
      a2 = fdot2f(p2, wzr[4*kk+2], a2);
      a3 = fdot2f(p3, wzr[4*kk+3], a3);
    }
    const half8_t* hh = hcur + (grpA ? 0 : 16);   // wave-uniform offset
    #pragma unroll
    for (int kk=0;kk<16;kk++){
      half8_t hv = hh[kk];
      half2_t p0 = {hv[0],hv[1]};
      half2_t p1 = {hv[2],hv[3]};
      half2_t p2 = {hv[4],hv[5]};
      half2_t p3 = {hv[6],hv[7]};
      c0 = fdot2f(p0, whh[4*kk+0], c0);
      c1 = fdot2f(p1, whh[4*kk+1], c1);
      c2 = fdot2f(p2, whh[4*kk+2], c2);
      c3 = fdot2f(p3, whh[4*kk+3], c3);
    }
    float azr = (a0+a1)+(a2+a3);
    float ah  = (c0+c1)+(c2+c3);
    if (!grpA){ sr[j] = azr; sh1[j] = ah; }
    __syncthreads();
    if (grpA){
      float z    = sigmoidf_(xpz + azr);
      float r    = sigmoidf_(xpr + sr[j]);
      float cand = tanhf_(xph + r*(ah + sh1[j]));
      hj = z*hj + (1.0f-z)*cand;
      ((_Float16*)hbuf[(g+1)&1])[j] = (_Float16)hj;
    }
    __syncthreads();
    xpz = nxz; xpr = nxr; xph = nxh;
  }

  // out = sigmoid(h . outW + outb)
  red[t] = grpA ? hj*outW[j] : 0.0f;
  __syncthreads();
  for (int st=256;st>0;st>>=1){
    if (t<st) red[t]+=red[t+st];
    __syncthreads();
  }
  if (t==0) out[b] = sigmoidf_(red[0]+outb[0]);
}

extern "C" void kernel_launch(void* const* d_in, const int* in_sizes, int n_in,
                              void* d_out, int out_size, void* d_ws, size_t ws_size,
                              hipStream_t stream) {
  const float* demo   = (const float*)d_in[0];
  const float* times  = (const float*)d_in[1];
  const float* values = (const float*)d_in[2];
  const float* meas   = (const float*)d_in[3];
  const float* grid   = (const float*)d_in[4];
  const float* ksic   = (const float*)d_in[5];
  const float* crossW = (const float*)d_in[6];
  const float* dW1    = (const float*)d_in[7];
  const float* db1    = (const float*)d_in[8];
  const float* dW2    = (const float*)d_in[9];
  const float* db2    = (const float*)d_in[10];
  const float* gWx    = (const float*)d_in[11];
  const float* gWh    = (const float*)d_in[12];
  const float* gb     = (const float*)d_in[13];
  const float* outW   = (const float*)d_in[14];
  const float* outb   = (const float*)d_in[15];
  const int*   lens   = (const int*)d_in[16];
  float* out = (float*)d_out;

  float* ws   = (float*)d_ws;
  float* y    = ws;                        // B*D*G
  float* w    = y    + B_*D_*G_;
  float* ytr  = w    + B_*D_*G_;
  float* mean = ytr  + B_*D_*G_;
  float* h0   = mean + B_*D_;
  float* xprj = h0   + B_*H_;              // B*G*768

  k_interp<<<B_*D_, 256, 0, stream>>>(times, values, meas, grid, ksic, y, w, ytr, mean);
  k_demo  <<<1,     256, 0, stream>>>(demo, dW1, db1, dW2, db2, h0);
  k_cross <<<B_*G_, 256, 0, stream>>>(y, w, ytr, mean, crossW, gWx, gb, lens, xprj);
  k_gru   <<<B_,    512, 0, stream>>>(gWh, gb, xprj, h0, lens, outW, outb, out);
}